// Round 3
// baseline (24429.015 us; speedup 1.0000x reference)
//
#include <hip/hip_runtime.h>
#include <math.h>

#define B    32
#define EMBD 1024
#define HID  1024
#define G    4096   // 4*HID
#define V    32000
#define TS   128
#define XROW (TS + 1)
#define KSL  16     // gate k-splits (chunk 64 = 4 ksub * 16)
#define KSF  2      // fc   k-splits (chunk 512 = 4 ksub * 128)
#define JBF  125    // fc j-blocks (125*256 = 32000)

#define FMA4(acc, W_, V_) \
  acc = fmaf((W_).x,(V_).x, fmaf((W_).y,(V_).y, fmaf((W_).z,(V_).z, fmaf((W_).w,(V_).w,(acc)))))

// ---------------- init: tok = x[:,0], h=c=0 ----------------
__global__ __launch_bounds__(256) void k_init(
    const int* __restrict__ x, int* __restrict__ tok,
    float* __restrict__ h, float* __restrict__ c)
{
    const int idx = blockIdx.x * 256 + threadIdx.x;   // grid 256 -> 65536
    h[idx] = 0.f;
    c[idx] = 0.f;
    if (idx < B) tok[idx] = x[idx * XROW];
}

// ---------------- LSTM gates partial GEMM (no-LDS inner loop) ----------------
// grid (16 jb, 16 ks), block 1024 = 256 j * 4 ksub. Each thread: 1 j, 16 k, 32 b.
// In-block 4-way ksub reduce -> gpart[ks][b][j].
__global__ __launch_bounds__(1024, 4) void k_lstm(
    const float* __restrict__ xsrc,   // emb (layer0) or h0 (layer1)
    const int* __restrict__ tok, int use_tok,
    const float* __restrict__ hprev,
    const float* __restrict__ Wih, const float* __restrict__ Whh,
    float* __restrict__ gpart)
{
    __shared__ float red[4 * B * 64];   // [ksub][b][jj] 32KB
    const int tid  = threadIdx.x;
    const int jl   = tid & 255;
    const int ksub = __builtin_amdgcn_readfirstlane(tid >> 8);
    const int jb   = blockIdx.x;        // 0..15
    const int ks   = blockIdx.y;        // 0..15
    const int j    = jb * 256 + jl;
    const int kbase = ks * 64 + ksub * 16;

    const float* wi = Wih + (size_t)j * EMBD + kbase;
    const float* wh = Whh + (size_t)j * HID  + kbase;
    float4 wiv[4], whv[4];
#pragma unroll
    for (int kk = 0; kk < 4; kk++) {
        wiv[kk] = *(const float4*)(wi + kk * 4);
        whv[kk] = *(const float4*)(wh + kk * 4);
    }

    float acc[B];
#pragma unroll
    for (int b = 0; b < B; b++) acc[b] = 0.f;

#pragma unroll
    for (int b = 0; b < B; b++) {
        const float* xr = use_tok ? (xsrc + (size_t)tok[b] * EMBD + kbase)
                                  : (xsrc + (size_t)b * EMBD + kbase);
        const float* hr = hprev + (size_t)b * HID + kbase;
#pragma unroll
        for (int kk = 0; kk < 4; kk++) {
            const float4 xv = *(const float4*)(xr + kk * 4);
            const float4 hv = *(const float4*)(hr + kk * 4);
            FMA4(acc[b], wiv[kk], xv);
            FMA4(acc[b], whv[kk], hv);
        }
    }

    // 4-way ksub reduce, 4 passes over j-quarters of 64
    for (int p = 0; p < 4; p++) {
        __syncthreads();
        if ((jl >> 6) == p) {
            const int jj = jl & 63;
#pragma unroll
            for (int b = 0; b < B; b++)
                red[(ksub * B + b) * 64 + jj] = acc[b];
        }
        __syncthreads();
#pragma unroll
        for (int q = 0; q < 2; q++) {
            const int u  = tid + q * 1024;     // 0..2047
            const int b  = u >> 6;
            const int jj = u & 63;
            const float v = red[(0 * B + b) * 64 + jj] + red[(1 * B + b) * 64 + jj]
                          + red[(2 * B + b) * 64 + jj] + red[(3 * B + b) * 64 + jj];
            gpart[((size_t)ks * B + b) * G + jb * 256 + p * 64 + jj] = v;
        }
    }
}

// ---------------- reduce gate partials + activations + state ----------------
// grid 128, block 256; idx = b*1024 + jh
__global__ __launch_bounds__(256) void k_act(
    const float* __restrict__ part, const float* __restrict__ bih,
    const float* __restrict__ bhh, float* __restrict__ c, float* __restrict__ h)
{
    const int idx = blockIdx.x * 256 + threadIdx.x;
    const int b = idx >> 10, jh = idx & 1023;
    float gi = bih[jh]        + bhh[jh];
    float gf = bih[jh + 1024] + bhh[jh + 1024];
    float gg = bih[jh + 2048] + bhh[jh + 2048];
    float go = bih[jh + 3072] + bhh[jh + 3072];
#pragma unroll
    for (int ks = 0; ks < KSL; ks++) {
        const float* p = part + ((size_t)ks * B + b) * G;
        gi += p[jh]; gf += p[jh + 1024]; gg += p[jh + 2048]; go += p[jh + 3072];
    }
    const float i = 1.f / (1.f + expf(-gi));
    const float f = 1.f / (1.f + expf(-gf));
    const float g = tanhf(gg);
    const float o = 1.f / (1.f + expf(-go));
    const float cn = f * c[idx] + i * g;
    c[idx] = cn;
    h[idx] = o * tanhf(cn);
}

// ---------------- FC partial GEMM (no-LDS inner loop) ----------------
// grid (125 jb, 2 ks), block 1024 = 256 j * 4 ksub. Each thread: 1 j, 128 k, 32 b.
__global__ __launch_bounds__(1024, 4) void k_fc(
    const float* __restrict__ h1, const float* __restrict__ W,
    float* __restrict__ fpart)
{
    __shared__ float red[4 * B * 64];
    const int tid  = threadIdx.x;
    const int jl   = tid & 255;
    const int ksub = __builtin_amdgcn_readfirstlane(tid >> 8);
    const int jb   = blockIdx.x;        // 0..124
    const int ks   = blockIdx.y;        // 0..1
    const int j    = jb * 256 + jl;
    const int kbase = ks * 512 + ksub * 128;

    const float* wr = W + (size_t)j * HID + kbase;

    float acc[B];
#pragma unroll
    for (int b = 0; b < B; b++) acc[b] = 0.f;

    for (int g = 0; g < 8; g++) {       // 8 groups of 16 k
        float4 w4[4];
#pragma unroll
        for (int kk = 0; kk < 4; kk++)
            w4[kk] = *(const float4*)(wr + g * 16 + kk * 4);
#pragma unroll
        for (int b = 0; b < B; b++) {
            const float* xr = h1 + (size_t)b * HID + kbase + g * 16;
#pragma unroll
            for (int kk = 0; kk < 4; kk++) {
                const float4 xv = *(const float4*)(xr + kk * 4);
                FMA4(acc[b], w4[kk], xv);
            }
        }
    }

    for (int p = 0; p < 4; p++) {
        __syncthreads();
        if ((jl >> 6) == p) {
            const int jj = jl & 63;
#pragma unroll
            for (int b = 0; b < B; b++)
                red[(ksub * B + b) * 64 + jj] = acc[b];
        }
        __syncthreads();
#pragma unroll
        for (int q = 0; q < 2; q++) {
            const int u  = tid + q * 1024;
            const int b  = u >> 6;
            const int jj = u & 63;
            const float v = red[(0 * B + b) * 64 + jj] + red[(1 * B + b) * 64 + jj]
                          + red[(2 * B + b) * 64 + jj] + red[(3 * B + b) * 64 + jj];
            fpart[((size_t)ks * B + b) * V + jb * 256 + p * 64 + jj] = v;
        }
    }
}

// ---------------- FC reduce + exp/max/argmax partials ----------------
// grid (125 jb, 32 b), block 256
__global__ __launch_bounds__(256) void k_fcsm(
    const float* __restrict__ fpart, const float* __restrict__ bfc,
    const int* __restrict__ x, int t,
    float* __restrict__ psum, float* __restrict__ pmax, int* __restrict__ pidx,
    float* __restrict__ lt)
{
    const int jb = blockIdx.x;   // 0..124
    const int b  = blockIdx.y;   // 0..31
    const int tid = threadIdx.x;
    const int j = jb * 256 + tid;
    const float l = bfc[j] + fpart[(size_t)(0 * B + b) * V + j]
                           + fpart[(size_t)(1 * B + b) * V + j];
    const int tgt = x[b * XROW + t + 1];
    if (j == tgt) lt[b] = l;

    __shared__ float ss[256], sm[256];
    __shared__ int si[256];
    ss[tid] = expf(l); sm[tid] = l; si[tid] = j;
    __syncthreads();
    for (int s = 128; s > 0; s >>= 1) {
        if (tid < s) {
            ss[tid] += ss[tid + s];
            const float mv = sm[tid + s]; const int mi = si[tid + s];
            if (mv > sm[tid] || (mv == sm[tid] && mi < si[tid])) {
                sm[tid] = mv; si[tid] = mi;
            }
        }
        __syncthreads();
    }
    if (tid == 0) {
        psum[b * JBF + jb] = ss[0];
        pmax[b * JBF + jb] = sm[0];
        pidx[b * JBF + jb] = si[0];
    }
}

// ---------------- finalize: p(target), argmax -> tok ----------------
// grid 32 (b), block 128
__global__ __launch_bounds__(128) void k_fin(
    const float* __restrict__ psum, const float* __restrict__ pmax,
    const int* __restrict__ pidx, const float* __restrict__ lt,
    int* __restrict__ tok, float* __restrict__ out, int t)
{
    const int b = blockIdx.x, tid = threadIdx.x;
    float s = 0.f, m = -1e30f; int mi = 0x7fffffff;
    if (tid < JBF) {
        s = psum[b * JBF + tid]; m = pmax[b * JBF + tid]; mi = pidx[b * JBF + tid];
    }
    __shared__ float ss[128], sm[128];
    __shared__ int si[128];
    ss[tid] = s; sm[tid] = m; si[tid] = mi;
    __syncthreads();
    for (int st = 64; st > 0; st >>= 1) {
        if (tid < st) {
            ss[tid] += ss[tid + st];
            const float mv = sm[tid + st]; const int ix = si[tid + st];
            if (mv > sm[tid] || (mv == sm[tid] && ix < si[tid])) {
                sm[tid] = mv; si[tid] = ix;
            }
        }
        __syncthreads();
    }
    if (tid == 0) {
        out[(size_t)b * TS + t] = expf(lt[b]) / ss[0];
        tok[b] = si[0];
    }
}

extern "C" void kernel_launch(void* const* d_in, const int* in_sizes, int n_in,
                              void* d_out, int out_size, void* d_ws, size_t ws_size,
                              hipStream_t stream)
{
    const int*   x   = (const int*)  d_in[0];
    const float* emb = (const float*)d_in[1];
    const float* Wih = (const float*)d_in[2];
    const float* Whh = (const float*)d_in[3];
    const float* bih = (const float*)d_in[4];
    const float* bhh = (const float*)d_in[5];
    const float* Wfc = (const float*)d_in[6];
    const float* bfc = (const float*)d_in[7];
    float* out = (float*)d_out;

    float* ws = (float*)d_ws;
    float* h     = ws;                                  // 2*B*HID
    float* c     = h + 2 * (size_t)B * HID;             // 2*B*HID
    float* gpart = c + 2 * (size_t)B * HID;             // KSL*B*G
    float* fpart = gpart + (size_t)KSL * B * G;         // KSF*B*V
    float* psum  = fpart + (size_t)KSF * B * V;         // B*JBF
    float* pmax  = psum + B * JBF;                      // B*JBF
    float* lt    = pmax + B * JBF;                      // B
    int*   pidx  = (int*)(lt + B);                      // B*JBF
    int*   tok   = pidx + B * JBF;                      // B

    float* h0 = h, *h1 = h + (size_t)B * HID;
    float* c0 = c, *c1 = c + (size_t)B * HID;

    k_init<<<256, 256, 0, stream>>>(x, tok, h, c);

    for (int t = 0; t < TS; t++) {
        // layer 0 (x = emb[tok])
        k_lstm<<<dim3(16, 16), 1024, 0, stream>>>(emb, tok, 1, h0, Wih, Whh, gpart);
        k_act<<<128, 256, 0, stream>>>(gpart, bih, bhh, c0, h0);
        // layer 1 (x = h0)
        k_lstm<<<dim3(16, 16), 1024, 0, stream>>>(h0, tok, 0, h1,
                                                  Wih + (size_t)G * EMBD,
                                                  Whh + (size_t)G * HID, gpart);
        k_act<<<128, 256, 0, stream>>>(gpart, bih + G, bhh + G, c1, h1);
        // FC + softmax partials + finalize
        k_fc<<<dim3(JBF, 2), 1024, 0, stream>>>(h1, Wfc, fpart);
        k_fcsm<<<dim3(JBF, B), 256, 0, stream>>>(fpart, bfc, x, t, psum, pmax, pidx, lt);
        k_fin<<<B, 128, 0, stream>>>(psum, pmax, pidx, lt, tok, out, t);
    }
}